// Round 4
// baseline (314.806 us; speedup 1.0000x reference)
//
#include <hip/hip_runtime.h>
#include <hip/hip_bf16.h>
#include <math.h>

#define EPS 1e-3f
// B=4, S=256, D=256, v=128, e=64, c=192, NH=8, DK=8, DV=8

// ws layout (float units):
// 8192   : cK[64], 8256: dK[64], 8320: cV[64], 8384: dV[64]
// 8448   : q_s [B*D*64]  (relu(q)/sqrt(8))
// 73984  : Pd  [B*D*64]  (V_dst @ We[128:256])
// 139520 : svssv float2[B*S]  (sum, sumsq of V_src row, interleaved)
// 141568 : QKV uint[B*S*64]  bf16 pair (k,v), layout [s][col][t] (col=n&15,t=n>>4)
// 207104 : Ps  [B*S*64] fp32 [s][n]  (V_src @ We[0:128])
// 272640 : A_T [B,D,S]  (transposed adjacency)
// 534784 : Wcat bf16 [192 n][64 k] = [g_in*WkE | g_in*WvE | We3] (12288 ushort)
#define SVSSV_OFF 139520
#define QKV_OFF   141568
#define PS_OFF    207104
#define AT_OFF    272640
#define WCAT_OFF  534784

typedef __attribute__((ext_vector_type(8))) short short8;
typedef __attribute__((ext_vector_type(8))) unsigned short ushort8;
typedef __attribute__((ext_vector_type(4))) float floatx4;

__device__ __forceinline__ unsigned short f2bf(float f) {
    __hip_bfloat16 h = __float2bfloat16(f);
    return *reinterpret_cast<unsigned short*>(&h);
}
__device__ __forceinline__ float bflo(unsigned int u) { return __uint_as_float(u << 16); }
__device__ __forceinline__ float bfhi(unsigned int u) { return __uint_as_float(u & 0xffff0000u); }

// Merged precompute: blocks 0..1023 = dst-mode (q_s, Pd, A_T, A_new=1 fill),
// 1024..2047 = src-mode (svssv, QKV bf16-pack, Ps), 2048 = weight-prep.
__global__ __launch_bounds__(256) void prep_merged(
        const float* __restrict__ V_src, const float* __restrict__ V_dst,
        const float* __restrict__ A,
        const float* __restrict__ g_vd, const float* __restrict__ b_vd,
        const float* __restrict__ g_in, const float* __restrict__ b_in,
        const float* __restrict__ Wq, const float* __restrict__ bq,
        const float* __restrict__ Wk, const float* __restrict__ bk,
        const float* __restrict__ Wv, const float* __restrict__ bv,
        const float* __restrict__ We, float* __restrict__ ws,
        float* __restrict__ out2) {
    int blk = blockIdx.x;
    int tid = threadIdx.x;
    __shared__ float sA[128], sB[128], sC[4];
    __shared__ float kv[128];
    if (blk < 1024) {
        int b = blk >> 8, d = blk & 255;
        // ---- dst-mode: LN(V_dst)->q, Pd; A_T; A_new = 1.0 fill ----
        float x = 0.f;
        if (tid < 128) { x = V_dst[blk * 128 + tid]; sA[tid] = x; }
        float s1 = x, s2 = x * x;
        #pragma unroll
        for (int o = 1; o <= 32; o <<= 1) { s1 += __shfl_xor(s1, o); s2 += __shfl_xor(s2, o); }
        if (tid < 128 && (tid & 63) == 0) { sC[tid >> 6] = s1; sC[2 + (tid >> 6)] = s2; }
        // A transpose: thread tid = s reads scattered, writes contiguous
        float av = A[(b * 256 + tid) * 256 + d];
        __syncthreads();
        if (tid < 128) {
            float sum = sC[0] + sC[1], ssq = sC[2] + sC[3];
            float mu = sum * (1.f / 128.f);
            float var = ssq * (1.f / 128.f) - mu * mu;
            float rsig = rsqrtf(var + EPS);
            sB[tid] = (x - mu) * rsig * g_vd[tid] + b_vd[tid];
        }
        __syncthreads();
        if (tid < 128) {
            int n = tid & 63;
            if (tid < 64) {
                float acc = bq[n];
                #pragma unroll 4
                for (int j = 0; j < 128; j++) acc += sB[j] * Wq[j * 64 + n];
                ws[8448 + blk * 64 + n] = fmaxf(acc, 0.f) * 0.35355339059327373f;
            } else {
                float acc = 0.f;
                #pragma unroll 4
                for (int j = 0; j < 128; j++) acc += sA[j] * We[(128 + j) * 64 + n];
                ws[73984 + blk * 64 + n] = acc;
            }
        }
        ws[AT_OFF + blk * 256 + tid] = av;
        out2[blk * 256 + tid] = 1.0f;   // A_new == softmax over singleton == 1
    } else if (blk < 2048) {
        // ---- src-mode: row stats (float2); QKV bf16 pack; Ps fp32 ----
        int sb = blk - 1024;
        if (tid < 128) sA[tid] = V_src[sb * 128 + tid];
        __syncthreads();
        if (tid < 64) {
            float a = sA[tid], b2 = sA[tid + 64];
            float s1 = a + b2, s2 = a * a + b2 * b2;
            #pragma unroll
            for (int o = 1; o <= 32; o <<= 1) { s1 += __shfl_xor(s1, o); s2 += __shfl_xor(s2, o); }
            if (tid == 0) { ws[SVSSV_OFF + 2 * sb] = s1; ws[SVSSV_OFF + 2 * sb + 1] = s2; }
        }
        if (tid < 192) {
            int g = tid / 64, n = tid & 63;
            float acc = 0.f;
            if (g == 0) {
                #pragma unroll 4
                for (int j = 0; j < 128; j++) acc += sA[j] * g_in[j] * Wk[j * 64 + n];
                kv[n] = acc;
            } else if (g == 1) {
                #pragma unroll 4
                for (int j = 0; j < 128; j++) acc += sA[j] * g_in[j] * Wv[j * 64 + n];
                kv[64 + n] = acc;
            } else {
                #pragma unroll 4
                for (int j = 0; j < 128; j++) acc += sA[j] * We[j * 64 + n];
                ws[PS_OFF + sb * 64 + n] = acc;
            }
        }
        __syncthreads();
        if (tid < 64) {
            // output slot tid: col = tid>>2, t = tid&3 -> n = t*16+col
            int colq = tid >> 2, tq = tid & 3, nn = tq * 16 + colq;
            unsigned int u = (unsigned int)f2bf(kv[nn]) | ((unsigned int)f2bf(kv[64 + nn]) << 16);
            ((unsigned int*)(ws + QKV_OFF))[sb * 64 + tid] = u;
        }
    } else {
        // ---- weight-prep (folded LN coefficients + bf16 Wcat) ----
        int n = tid & 63;
        if (tid < 64) {
            float c = 0.f, dd = 0.f;
            for (int j = 0; j < 192; j++) { float w = Wk[j * 64 + n]; c += g_in[j] * w; dd += b_in[j] * w; }
            ws[8192 + n] = c; ws[8256 + n] = dd + bk[n];
        } else if (tid < 128) {
            float c = 0.f, dd = 0.f;
            for (int j = 0; j < 192; j++) { float w = Wv[j * 64 + n]; c += g_in[j] * w; dd += b_in[j] * w; }
            ws[8320 + n] = c; ws[8384 + n] = dd + bv[n];
        }
        unsigned short* wcat = (unsigned short*)(ws + WCAT_OFF);
        for (int idx = tid; idx < 12288; idx += 256) {
            int nn = idx >> 6, k = idx & 63;
            float w;
            if (nn < 64)       w = g_in[128 + k] * Wk[(128 + k) * 64 + nn];
            else if (nn < 128) w = g_in[128 + k] * Wv[(128 + k) * 64 + (nn - 64)];
            else               w = We[(256 + k) * 64 + (nn - 128)];
            wcat[idx] = f2bf(w);
        }
    }
}

// Fused per-(b,d) kernel, MFMA-layout epilogue.
//   phase1/2 (K,V): mfma(E,W) -> n = t*16+col, row = quad*4+r; softmax over
//   heads: dk=col&7 (shfl 1,2,4), head bit0 = col>>3 (shfl 8), bits1-2 = t.
//   phase3 (pe): operands SWAPPED mfma(W,E) -> lane holds 4 consecutive n's
//   for e-row=col => float4 coalesced E_new stores.
// Round-4: bf16 QKV pair loads (1x16B per row), A_T/svssv packed loads,
//   E register double-buffer. All to cut L2-miss slot time (round-3 model).
__global__ __launch_bounds__(256, 4) void fused_kernel(
        const float* __restrict__ E,
        const float* __restrict__ V_dst,
        const float* __restrict__ Wo, const float* __restrict__ bo,
        const float* __restrict__ be,
        const float* __restrict__ ws,
        float* __restrict__ out0, float* __restrict__ out1) {
    int blk = ((blockIdx.x & 7) << 7) | (blockIdx.x >> 3);   // XCD-contiguous work id
    int b = blk >> 8, d = blk & 255;
    int tid = threadIdx.x, wv = tid >> 6, lane = tid & 63;
    int col = lane & 15, quad = lane >> 4;

    __shared__ __align__(16) unsigned short Ebf[64 * 72];   // 64 rows x 64 bf16, stride 72
    __shared__ __align__(16) unsigned short Wc[192 * 72];   // Wcat, stride 72
    __shared__ float ssum[64], sssq[64];
    __shared__ float osm[4][64];
    __shared__ float otot[64];

    // one-time: copy packed Wcat [192][64] -> LDS with pad stride 72
    {
        const unsigned int* wsrc = (const unsigned int*)(ws + WCAT_OFF);
        for (int i = tid; i < 6144; i += 256)
            *(unsigned int*)(Wc + (i >> 5) * 72 + (i & 31) * 2) = wsrc[i];
    }

    // persistent per-lane params for n = t*16+col (phase 1/2 orientation)
    float cK[4], dK[4], cV[4], dV[4], qsc[4];
    #pragma unroll
    for (int t = 0; t < 4; t++) {
        int n = t * 16 + col;
        cK[t] = ws[8192 + n]; dK[t] = ws[8256 + n];
        cV[t] = ws[8320 + n]; dV[t] = ws[8384 + n];
        qsc[t] = ws[8448 + blk * 64 + n];
    }
    const float2* svp = (const float2*)(ws + SVSSV_OFF) + b * 256;
    const unsigned int* qkv = (const unsigned int*)(ws + QKV_OFF) + (size_t)b * 16384;
    const float* Ps  = ws + PS_OFF + (size_t)b * 16384;
    const float* At  = ws + AT_OFF + blk * 256;
    const float* pdvp = ws + 73984 + blk * 64;

    float o0 = 0.f, o1 = 0.f, o2 = 0.f, o3 = 0.f;
    int rstage = tid >> 2, gstage = tid & 3;

    // E prefetch (chunk 0) into registers
    const float* ep = E + ((size_t)((b * 256 + rstage) * 256 + d)) * 64 + gstage * 16;
    float4 e0 = *(const float4*)(ep);
    float4 e1 = *(const float4*)(ep + 4);
    float4 e2 = *(const float4*)(ep + 8);
    float4 e3 = *(const float4*)(ep + 12);

    __syncthreads();   // Wc ready (only barrier before final epilogue)

    #pragma unroll
    for (int chunk = 0; chunk < 4; chunk++) {
        int s0 = chunk * 64;
        // ---- stage 64 rows of E (regs -> bf16 LDS) + fp32 row stats (wave-local) ----
        {
            float s1 = (e0.x + e0.y + e0.z + e0.w) + (e1.x + e1.y + e1.z + e1.w)
                     + (e2.x + e2.y + e2.z + e2.w) + (e3.x + e3.y + e3.z + e3.w);
            float s2 = (e0.x*e0.x + e0.y*e0.y + e0.z*e0.z + e0.w*e0.w)
                     + (e1.x*e1.x + e1.y*e1.y + e1.z*e1.z + e1.w*e1.w)
                     + (e2.x*e2.x + e2.y*e2.y + e2.z*e2.z + e2.w*e2.w)
                     + (e3.x*e3.x + e3.y*e3.y + e3.z*e3.z + e3.w*e3.w);
            s1 += __shfl_xor(s1, 1); s2 += __shfl_xor(s2, 1);
            s1 += __shfl_xor(s1, 2); s2 += __shfl_xor(s2, 2);
            if (gstage == 0) { ssum[rstage] = s1; sssq[rstage] = s2; }
            ushort8 w0, w1;
            w0[0]=f2bf(e0.x); w0[1]=f2bf(e0.y); w0[2]=f2bf(e0.z); w0[3]=f2bf(e0.w);
            w0[4]=f2bf(e1.x); w0[5]=f2bf(e1.y); w0[6]=f2bf(e1.z); w0[7]=f2bf(e1.w);
            w1[0]=f2bf(e2.x); w1[1]=f2bf(e2.y); w1[2]=f2bf(e2.z); w1[3]=f2bf(e2.w);
            w1[4]=f2bf(e3.x); w1[5]=f2bf(e3.y); w1[6]=f2bf(e3.z); w1[7]=f2bf(e3.w);
            *(ushort8*)(Ebf + rstage * 72 + gstage * 16)     = w0;
            *(ushort8*)(Ebf + rstage * 72 + gstage * 16 + 8) = w1;
        }
        // ---- E register double-buffer: issue next chunk's loads now ----
        if (chunk < 3) {
            ep += 1048576;   // 64 s-rows * 256 d * 64
            e0 = *(const float4*)(ep);
            e1 = *(const float4*)(ep + 4);
            e2 = *(const float4*)(ep + 8);
            e3 = *(const float4*)(ep + 12);
        }
        // ---- hoisted per-chunk epilogue loads (wide) ----
        int sq = s0 + wv * 16 + quad * 4;        // this lane's quad-row base
        float4 aL4 = *(const float4*)(At + sq);  // A for rows r=0..3
        uint4 kvL[4];
        #pragma unroll
        for (int r = 0; r < 4; r++)
            kvL[r] = *(const uint4*)(qkv + (size_t)(sq + r) * 64 + col * 4);

        // ---- A fragments (wave-local rows) ----
        short8 a0 = *(const short8*)(Ebf + (wv * 16 + col) * 72 + quad * 8);
        short8 a1 = *(const short8*)(Ebf + (wv * 16 + col) * 72 + 32 + quad * 8);

        // ---- phase 1: qek / qev tiles (mfma(E,W): n on col, row on quad) ----
        floatx4 ak[4], av[4];
        #pragma unroll
        for (int t = 0; t < 4; t++) {
            const unsigned short* wp = Wc + (t * 16 + col) * 72 + quad * 8;
            floatx4 acc = {0.f, 0.f, 0.f, 0.f};
            acc = __builtin_amdgcn_mfma_f32_16x16x32_bf16(a0, *(const short8*)(wp),      acc, 0, 0, 0);
            acc = __builtin_amdgcn_mfma_f32_16x16x32_bf16(a1, *(const short8*)(wp + 32), acc, 0, 0, 0);
            ak[t] = acc;
        }
        #pragma unroll
        for (int t = 0; t < 4; t++) {
            const unsigned short* wp = Wc + (64 + t * 16 + col) * 72 + quad * 8;
            floatx4 acc = {0.f, 0.f, 0.f, 0.f};
            acc = __builtin_amdgcn_mfma_f32_16x16x32_bf16(a0, *(const short8*)(wp),      acc, 0, 0, 0);
            acc = __builtin_amdgcn_mfma_f32_16x16x32_bf16(a1, *(const short8*)(wp + 32), acc, 0, 0, 0);
            av[t] = acc;
        }

        // ---- phase 2: softmax-over-heads + attention, in MFMA layout ----
        #pragma unroll
        for (int r = 0; r < 4; r++) {
            int sl = wv * 16 + quad * 4 + r;
            int s = s0 + sl;
            float a = (r == 0) ? aL4.x : (r == 1) ? aL4.y : (r == 2) ? aL4.z : aL4.w;
            float2 ss = svp[s];
            float mu  = (a * ss.x + ssum[sl]) * (1.f / 192.f);
            float ex2 = (a * a * ss.y + sssq[sl]) * (1.f / 192.f);
            float rsig = rsqrtf(ex2 - mu * mu + EPS);
            float rm = rsig * mu;
            uint4 kvr = kvL[r];
            float h0 = qsc[0] * fmaxf(rsig * (a * bflo(kvr.x) + ak[0][r]) - rm * cK[0] + dK[0], 0.f);
            float h1 = qsc[1] * fmaxf(rsig * (a * bflo(kvr.y) + ak[1][r]) - rm * cK[1] + dK[1], 0.f);
            float h2 = qsc[2] * fmaxf(rsig * (a * bflo(kvr.z) + ak[2][r]) - rm * cK[2] + dK[2], 0.f);
            float h3 = qsc[3] * fmaxf(rsig * (a * bflo(kvr.w) + ak[3][r]) - rm * cK[3] + dK[3], 0.f);
            // dot over dk (lane bits 0..2)
            h0 += __shfl_xor(h0, 1); h1 += __shfl_xor(h1, 1); h2 += __shfl_xor(h2, 1); h3 += __shfl_xor(h3, 1);
            h0 += __shfl_xor(h0, 2); h1 += __shfl_xor(h1, 2); h2 += __shfl_xor(h2, 2); h3 += __shfl_xor(h3, 2);
            h0 += __shfl_xor(h0, 4); h1 += __shfl_xor(h1, 4); h2 += __shfl_xor(h2, 4); h3 += __shfl_xor(h3, 4);
            // softmax over 8 heads: 4 in registers + 1 lane-xor-8
            float m = fmaxf(fmaxf(h0, h1), fmaxf(h2, h3));
            m = fmaxf(m, __shfl_xor(m, 8));
            float p0 = __expf(h0 - m), p1 = __expf(h1 - m), p2 = __expf(h2 - m), p3 = __expf(h3 - m);
            float den = (p0 + p1) + (p2 + p3);
            den += __shfl_xor(den, 8);
            float inv = 1.f / den;
            float vl0 = fmaxf(rsig * (a * bfhi(kvr.x) + av[0][r]) - rm * cV[0] + dV[0], 0.f);
            float vl1 = fmaxf(rsig * (a * bfhi(kvr.y) + av[1][r]) - rm * cV[1] + dV[1], 0.f);
            float vl2 = fmaxf(rsig * (a * bfhi(kvr.z) + av[2][r]) - rm * cV[2] + dV[2], 0.f);
            float vl3 = fmaxf(rsig * (a * bfhi(kvr.w) + av[3][r]) - rm * cV[3] + dV[3], 0.f);
            o0 += p0 * inv * vl0; o1 += p1 * inv * vl1;
            o2 += p2 * inv * vl2; o3 += p3 * inv * vl3;
        }

        // ---- phase 3: pe tiles with SWAPPED operands (mfma(W,E)):
        //      lane (quad,col) holds e-row=col, n = t*16 + quad*4 + {0..3} ----
        floatx4 ap[4];
        #pragma unroll
        for (int t = 0; t < 4; t++) {
            const unsigned short* wp = Wc + (128 + t * 16 + col) * 72 + quad * 8;
            floatx4 acc = {0.f, 0.f, 0.f, 0.f};
            acc = __builtin_amdgcn_mfma_f32_16x16x32_bf16(*(const short8*)(wp),      a0, acc, 0, 0, 0);
            acc = __builtin_amdgcn_mfma_f32_16x16x32_bf16(*(const short8*)(wp + 32), a1, acc, 0, 0, 0);
            ap[t] = acc;
        }
        {
            int sc = s0 + wv * 16 + col;           // this lane's e-row
            float a_c = At[sc];
            size_t base = ((size_t)((b * 256 + sc) * 256 + d)) * 64;
            #pragma unroll
            for (int t = 0; t < 4; t++) {
                int n0 = t * 16 + quad * 4;
                float4 ps  = *(const float4*)(Ps + (size_t)sc * 64 + n0);
                float4 pdv = *(const float4*)(pdvp + n0);
                float4 beq = *(const float4*)(be + n0);
                float4 v;
                v.x = fmaxf(a_c * (ps.x + pdv.x) + ap[t][0] + beq.x, 0.f);
                v.y = fmaxf(a_c * (ps.y + pdv.y) + ap[t][1] + beq.y, 0.f);
                v.z = fmaxf(a_c * (ps.z + pdv.z) + ap[t][2] + beq.z, 0.f);
                v.w = fmaxf(a_c * (ps.w + pdv.w) + ap[t][3] + beq.w, 0.f);
                *(float4*)(out1 + base + n0) = v;
            }
        }
    }

    // ---- o reduction: over quads in-register, then cross-wave via LDS ----
    o0 += __shfl_xor(o0, 16); o0 += __shfl_xor(o0, 32);
    o1 += __shfl_xor(o1, 16); o1 += __shfl_xor(o1, 32);
    o2 += __shfl_xor(o2, 16); o2 += __shfl_xor(o2, 32);
    o3 += __shfl_xor(o3, 16); o3 += __shfl_xor(o3, 32);
    float oval = (quad == 0) ? o0 : (quad == 1) ? o1 : ((quad == 2) ? o2 : o3);
    osm[wv][lane] = oval;     // lane = quad*16+col == n
    __syncthreads();
    if (tid < 64) otot[tid] = osm[0][tid] + osm[1][tid] + osm[2][tid] + osm[3][tid];
    __syncthreads();
    if (tid < 128) {
        float acc = bo[tid];
        #pragma unroll 4
        for (int n = 0; n < 64; n++) acc += otot[n] * Wo[n * 128 + tid];
        out0[blk * 128 + tid] = V_dst[blk * 128 + tid] + fmaxf(acc, 0.f);
    }
}

extern "C" void kernel_launch(void* const* d_in, const int* in_sizes, int n_in,
                              void* d_out, int out_size, void* d_ws, size_t ws_size,
                              hipStream_t stream) {
    (void)in_sizes; (void)n_in; (void)out_size; (void)ws_size;
    const float* V_src = (const float*)d_in[0];
    const float* V_dst = (const float*)d_in[1];
    const float* E     = (const float*)d_in[2];
    const float* A     = (const float*)d_in[3];
    const float* g_vd  = (const float*)d_in[4];
    const float* b_vd  = (const float*)d_in[5];
    const float* g_in  = (const float*)d_in[6];
    const float* b_in  = (const float*)d_in[7];
    const float* Wq    = (const float*)d_in[8];
    const float* bq    = (const float*)d_in[9];
    const float* Wk    = (const float*)d_in[10];
    const float* bk    = (const float*)d_in[11];
    const float* Wv    = (const float*)d_in[12];
    const float* bv    = (const float*)d_in[13];
    const float* Wo    = (const float*)d_in[14];
    const float* bo    = (const float*)d_in[15];
    const float* We    = (const float*)d_in[16];
    const float* be    = (const float*)d_in[17];
    float* ws   = (float*)d_ws;
    float* out0 = (float*)d_out;
    float* out1 = out0 + 131072;            // E_new [B,S,D,64]
    float* out2 = out1 + 16777216;          // A_new [B,S,D]

    hipLaunchKernelGGL(prep_merged, dim3(2049), dim3(256), 0, stream,
                       V_src, V_dst, A, g_vd, b_vd, g_in, b_in, Wq, bq, Wk, bk, Wv, bv, We, ws, out2);
    hipLaunchKernelGGL(fused_kernel, dim3(1024), dim3(256), 0, stream,
                       E, V_dst, Wo, bo, be, ws, out0, out1);
}